// Round 18
// baseline (104.628 us; speedup 1.0000x reference)
//
#include <hip/hip_runtime.h>

#define DZ 512
#define DT 66048
#define NTILE 2064  // 32-col tiles
#define SV_JITTER 1e-4f

typedef __attribute__((ext_vector_type(8))) short bf8;
typedef __attribute__((ext_vector_type(4))) short bf4;
typedef __attribute__((ext_vector_type(4))) float f4;

__device__ __forceinline__ short f2bf(float f) {
  unsigned u = __builtin_bit_cast(unsigned, f);
  return (short)((u + 0x7FFFu + ((u >> 16) & 1u)) >> 16);
}

__device__ __forceinline__ bf8 cvt8(f4 a, f4 b) {
  bf8 r = { f2bf(a[0]), f2bf(a[1]), f2bf(a[2]), f2bf(a[3]),
            f2bf(b[0]), f2bf(b[1]), f2bf(b[2]), f2bf(b[3]) };
  return r;
}

// tril/jitter cvt: element t has k-index kbase+t
__device__ __forceinline__ bf8 cvt8_tril(f4 x, f4 y, int kbase, int diag) {
  bf8 r;
  #pragma unroll
  for (int t = 0; t < 8; ++t) {
    const int k = kbase + t;
    const float vt = (t < 4) ? x[t] : y[t - 4];
    const float val = (k < diag) ? vt : ((k == diag) ? vt + SV_JITTER : 0.f);
    r[t] = f2bf(val);
  }
  return r;
}

// 256 blocks (1/CU) x 512 threads (8 waves). A in REGISTERS: wave wv holds
// af[16] = eps_z rows 16wv..+15 as bf16 MFMA fragments (64 VGPR, static
// indices; launch_bounds(512,1) raises the VGPR cap -- the R8/R10/R12 spills
// were 64/128-reg compiler caps). LDS = ONLY the double-buffered B panel
// (2 x 32KB, row-major [32][512] bf16, 16B-slot XOR swizzle, tril/jitter
// baked at stage time -- R13-proven layout).
// Round r (ONE barrier): compute T_r from Bpan[r&1] (reg-A + LDS-B + MFMA,
// zero global) -> store out -> stage_write T_{r+1} (sv regs loaded a full
// round ago: zero vmcnt stall) -> issue T_{r+2} loads (contiguous 64KB slab,
// 1KB per wave-instr sequential bursts) -> barrier. Stream is continuous.
// acc layout per mfma_f32_16x16x32_bf16: col=lane&15, row=4*(lane>>4)+reg.
__global__ __launch_bounds__(512, 1)
void sv_kernel(const float* __restrict__ mv, const float* __restrict__ Lz,
               const float* __restrict__ Ly, const float* __restrict__ Lyz,
               const float* __restrict__ eps, float* __restrict__ out) {
  __shared__ short Bpan[2][32 * 512];  // 2 x 32 KB

  const int tid = threadIdx.x;
  const int lane = tid & 63;
  const int wv = tid >> 6;  // 0..7 = sample group (rows 16wv..+15)
  const int lcol = lane & 15;
  const int q = lane >> 4;
  const int b = blockIdx.x;

  f4 sv[8];  // staged panel floats (32 VGPR), static indices only
  auto stage_load = [&](int T) {
    const float* Ls = (T < 16) ? (Lz + (size_t)(32 * T) * DZ)
                               : (Lyz + (size_t)(32 * T - DZ) * DZ);
    #pragma unroll
    for (int i = 0; i < 8; ++i)
      sv[i] = *(const f4*)(Ls + (size_t)4 * (i * 512 + tid));
  };
  // float4 f covers panel row ro=f>>7, k=4*(f&127)..+3 -> 8B bf16 at
  // ro*1024 + ((slot16 ^ (ro&7))<<4) + (c4&1)*8, slot16=c4>>1 (R13-proven).
  auto stage_write = [&](int T, short* buf) {
    #pragma unroll
    for (int i = 0; i < 8; ++i) {
      const int f = i * 512 + tid;
      const int ro = f >> 7;
      const int c4 = f & 127;
      bf4 w;
      if (T < 16) {  // z tile: tril + jitter baked in at stage time
        const int gcol = 32 * T + ro;
        #pragma unroll
        for (int t = 0; t < 4; ++t) {
          const int k = 4 * c4 + t;
          const float val =
              (k < gcol) ? sv[i][t] : ((k == gcol) ? sv[i][t] + SV_JITTER : 0.f);
          w[t] = f2bf(val);
        }
      } else {
        #pragma unroll
        for (int t = 0; t < 4; ++t) w[t] = f2bf(sv[i][t]);
      }
      const int off = (ro << 10) + ((((c4 >> 1) ^ (ro & 7))) << 4) + ((c4 & 1) << 3);
      *(bf4*)((char*)buf + off) = w;
    }
  };
  // B-frag read: row R=16g+lcol, k0=32kk+8q -> swizzled 16B slot 4kk+q
  auto readB = [&](const short* buf, int g, int kk) -> bf8 {
    const int R = 16 * g + lcol;
    const int off = (R << 10) + (((4 * kk + q) ^ (R & 7)) << 4);
    return *(const bf8*)((const char*)buf + off);
  };

  // ---- prologue: T0 panel stream first (oldest), af[16] from global
  stage_load(b);
  bf8 af[16];
  {
    const float* ar = eps + (size_t)(16 * wv + lcol) * DT + 8 * q;
    #pragma unroll
    for (int kk = 0; kk < 16; ++kk) {
      const f4 x = *(const f4*)(ar + 32 * kk);
      const f4 y = *(const f4*)(ar + 32 * kk + 4);
      af[kk] = cvt8(x, y);
    }
  }
  stage_write(b, Bpan[0]);  // waits T0 panel loads
  stage_load(b + 256);      // issue T1 stream (always valid: b+256 < 2064)
  __syncthreads();

  #pragma unroll 1
  for (int r = 0; r < 9; ++r) {
    const int T = r * 256 + b;
    if (T >= NTILE) break;
    const bool isz = (T < 16);

    // diag-step loads (y tiles): L2/L3-hot, land under compute
    f4 dax, day, db0x, db0y, db1x, db1y;
    if (!isz) {
      const int nb = T - 16;  // 32x32 Ly block
      const float* pa =
          eps + (size_t)(16 * wv + lcol) * DT + DZ + (size_t)nb * 32 + 8 * q;
      dax = *(const f4*)pa; day = *(const f4*)(pa + 4);
      const float* pb0 = Ly + ((size_t)nb * 32 + lcol) * 32 + 8 * q;
      db0x = *(const f4*)pb0; db0y = *(const f4*)(pb0 + 4);
      const float* pb1 = Ly + ((size_t)nb * 32 + 16 + lcol) * 32 + 8 * q;
      db1x = *(const f4*)pb1; db1y = *(const f4*)(pb1 + 4);
    }

    // ---- compute: reg-A + LDS-B + MFMA only
    const short* buf = Bpan[r & 1];
    f4 acc0 = f4{0.f, 0.f, 0.f, 0.f};
    f4 acc1 = f4{0.f, 0.f, 0.f, 0.f};
    #pragma unroll
    for (int kk = 0; kk < 16; ++kk) {
      const bf8 b0 = readB(buf, 0, kk);
      const bf8 b1 = readB(buf, 1, kk);
      acc0 = __builtin_amdgcn_mfma_f32_16x16x32_bf16(af[kk], b0, acc0, 0, 0, 0);
      acc1 = __builtin_amdgcn_mfma_f32_16x16x32_bf16(af[kk], b1, acc1, 0, 0, 0);
    }
    if (!isz) {  // block-diag einsum step
      const bf8 afd = cvt8(dax, day);
      const bf8 dbf0 = cvt8_tril(db0x, db0y, 8 * q, lcol);
      const bf8 dbf1 = cvt8_tril(db1x, db1y, 8 * q, 16 + lcol);
      acc0 = __builtin_amdgcn_mfma_f32_16x16x32_bf16(afd, dbf0, acc0, 0, 0, 0);
      acc1 = __builtin_amdgcn_mfma_f32_16x16x32_bf16(afd, dbf1, acc1, 0, 0, 0);
    }

    // ---- epilogue: both 64B halves of each 128B out line, back-to-back
    {
      const int c0 = 32 * T + lcol;
      const float m0 = mv[c0], m1 = mv[c0 + 16];
      #pragma unroll
      for (int rr = 0; rr < 4; ++rr) {
        const size_t rowoff = (size_t)(16 * wv + 4 * q + rr) * DT;
        out[rowoff + c0] = acc0[rr] + m0;
        out[rowoff + c0 + 16] = acc1[rr] + m1;
      }
    }

    // ---- pipeline: write T+1 panel (regs landed a round ago -> no stall),
    //      then issue T+2 stream; one barrier closes the round
    if (T + 256 < NTILE) stage_write(T + 256, Bpan[(r + 1) & 1]);
    if (T + 512 < NTILE) stage_load(T + 512);
    __syncthreads();
  }
}

extern "C" void kernel_launch(void* const* d_in, const int* in_sizes, int n_in,
                              void* d_out, int out_size, void* d_ws, size_t ws_size,
                              hipStream_t stream) {
  const float* m   = (const float*)d_in[0];
  const float* Lz  = (const float*)d_in[1];
  const float* Ly  = (const float*)d_in[2];
  const float* Lyz = (const float*)d_in[3];
  const float* eps = (const float*)d_in[4];
  float* out = (float*)d_out;
  sv_kernel<<<dim3(256), dim3(512), 0, stream>>>(m, Lz, Ly, Lyz, eps, out);
}

// Round 19
// 51.173 us; speedup vs baseline: 2.0446x; 2.0446x over previous
//
#include <hip/hip_runtime.h>

#define DZ 512
#define DT 66048
#define NTILE 2064  // 32-col tiles
#define SV_JITTER 1e-4f

typedef __attribute__((ext_vector_type(8))) short bf8;
typedef __attribute__((ext_vector_type(4))) short bf4;
typedef __attribute__((ext_vector_type(4))) float f4;

// Raw barrier: waits ONLY lgkmcnt (LDS visibility), NOT vmcnt -- in-flight
// global loads/stores survive the barrier (unlike __syncthreads, which
// drains vmcnt(0) and serializes the panel stream every round).
#define BAR()                                                   \
  do {                                                          \
    __builtin_amdgcn_sched_barrier(0);                          \
    asm volatile("s_waitcnt lgkmcnt(0)" ::: "memory");          \
    __builtin_amdgcn_s_barrier();                               \
    __builtin_amdgcn_sched_barrier(0);                          \
  } while (0)

__device__ __forceinline__ short f2bf(float f) {
  unsigned u = __builtin_bit_cast(unsigned, f);
  return (short)((u + 0x7FFFu + ((u >> 16) & 1u)) >> 16);
}

__device__ __forceinline__ bf8 cvt8(f4 a, f4 b) {
  bf8 r = { f2bf(a[0]), f2bf(a[1]), f2bf(a[2]), f2bf(a[3]),
            f2bf(b[0]), f2bf(b[1]), f2bf(b[2]), f2bf(b[3]) };
  return r;
}

// tril/jitter cvt: element t has k-index kbase+t
__device__ __forceinline__ bf8 cvt8_tril(f4 x, f4 y, int kbase, int diag) {
  bf8 r;
  #pragma unroll
  for (int t = 0; t < 8; ++t) {
    const int k = kbase + t;
    const float vt = (t < 4) ? x[t] : y[t - 4];
    const float val = (k < diag) ? vt : ((k == diag) ? vt + SV_JITTER : 0.f);
    r[t] = f2bf(val);
  }
  return r;
}

// R13 champion structure (50.8us) with __syncthreads -> raw lgkm-only
// barriers. 256 blocks (1/CU) x 512 threads (8 waves). LDS = 160KB:
//   Afrag 128KB: eps_z bf16, frag layout (region kk*8+mi, slot=lane), ONCE.
//   Bpan   32KB: tile B panel row-major [32][512] bf16, 16B-slot XOR swizzle,
//                tril/jitter baked at stage time.
// Per round: contiguous 64KB slab read as 8 x 1KB-per-wave-instr sequential
// bursts -> 32 VGPR -> LDS (load-early/write-late). K-loop: pure ds_read+MFMA.
// acc layout per mfma_f32_16x16x32_bf16: col=lane&15, row=4*(lane>>4)+reg.
__global__ __launch_bounds__(512, 2)
void sv_kernel(const float* __restrict__ mv, const float* __restrict__ Lz,
               const float* __restrict__ Ly, const float* __restrict__ Lyz,
               const float* __restrict__ eps, float* __restrict__ out) {
  __shared__ short Afrag[128 * 512];  // 128 KB
  __shared__ short Bpan[32 * 512];    //  32 KB

  const int tid = threadIdx.x;
  const int lane = tid & 63;
  const int wv = tid >> 6;  // 0..7 = sample group (rows 16wv..+15)
  const int lcol = lane & 15;
  const int q = lane >> 4;
  const int b = blockIdx.x;

  f4 sv[8];  // staged panel floats (32 VGPR), static indices only
  auto stage_load = [&](int T) {
    const float* Ls = (T < 16) ? (Lz + (size_t)(32 * T) * DZ)
                               : (Lyz + (size_t)(32 * T - DZ) * DZ);
    #pragma unroll
    for (int i = 0; i < 8; ++i)
      sv[i] = *(const f4*)(Ls + (size_t)4 * (i * 512 + tid));
  };
  // float4 f covers panel row ro=f>>7, k=4*(f&127)..+3 -> 8B bf16 at
  // ro*1024 + ((slot16 ^ (ro&7))<<4) + (c4&1)*8, slot16=c4>>1.
  auto stage_write = [&](int T) {
    #pragma unroll
    for (int i = 0; i < 8; ++i) {
      const int f = i * 512 + tid;
      const int ro = f >> 7;
      const int c4 = f & 127;
      bf4 w;
      if (T < 16) {  // z tile: tril + jitter baked in at stage time
        const int gcol = 32 * T + ro;
        #pragma unroll
        for (int t = 0; t < 4; ++t) {
          const int k = 4 * c4 + t;
          const float val =
              (k < gcol) ? sv[i][t] : ((k == gcol) ? sv[i][t] + SV_JITTER : 0.f);
          w[t] = f2bf(val);
        }
      } else {
        #pragma unroll
        for (int t = 0; t < 4; ++t) w[t] = f2bf(sv[i][t]);
      }
      const int off = (ro << 10) + ((((c4 >> 1) ^ (ro & 7))) << 4) + ((c4 & 1) << 3);
      *(bf4*)((char*)Bpan + off) = w;
    }
  };
  // B-frag read: row R=16g+lcol, k0=32kk+8q -> swizzled 16B slot 4kk+q
  auto readB = [&](int g, int kk) -> bf8 {
    const int R = 16 * g + lcol;
    const int off = (R << 10) + (((4 * kk + q) ^ (R & 7)) << 4);
    return *(const bf8*)((const char*)Bpan + off);
  };

  // ---- prologue: issue tile(b) panel stream (oldest), stage Afrag once
  stage_load(b);
  {  // eps_z -> Afrag: region r = kk*8+mi, slot=lane
    const int slot = lane;
    const int r0 = wv * 16;
    #pragma unroll 4
    for (int i = 0; i < 16; ++i) {
      const int r = r0 + i;  // mi=r&7, kk=r>>3
      const float* p = eps + (size_t)(16 * (r & 7) + (slot & 15)) * DT +
                       (r >> 3) * 32 + (slot >> 4) * 8;
      const f4 x = *(const f4*)p;
      const f4 y = *(const f4*)(p + 4);
      *(bf8*)&Afrag[r * 512 + slot * 8] = cvt8(x, y);
    }
  }
  stage_write(b);
  BAR();

  #pragma unroll 1
  for (int r = 0; r < 9; ++r) {
    const int T = r * 256 + b;
    if (T >= NTILE) break;
    const bool isz = (T < 16);
    const int Tn = T + 256;
    const bool have_next = (Tn < NTILE);

    if (have_next) stage_load(Tn);  // sequential burst, oldest vmem of round

    // diag-step loads (y tiles): land under compute
    f4 dax, day, db0x, db0y, db1x, db1y;
    if (!isz) {
      const int nb = T - 16;  // 32x32 Ly block
      const float* pa =
          eps + (size_t)(16 * wv + lcol) * DT + DZ + (size_t)nb * 32 + 8 * q;
      dax = *(const f4*)pa; day = *(const f4*)(pa + 4);
      const float* pb0 = Ly + ((size_t)nb * 32 + lcol) * 32 + 8 * q;
      db0x = *(const f4*)pb0; db0y = *(const f4*)(pb0 + 4);
      const float* pb1 = Ly + ((size_t)nb * 32 + 16 + lcol) * 32 + 8 * q;
      db1x = *(const f4*)pb1; db1y = *(const f4*)(pb1 + 4);
    }

    // ---- compute: pure LDS + MFMA (both operands pre-converted bf16)
    f4 acc0 = f4{0.f, 0.f, 0.f, 0.f};
    f4 acc1 = f4{0.f, 0.f, 0.f, 0.f};
    #pragma unroll
    for (int kk = 0; kk < 16; ++kk) {
      const bf8 af = *(const bf8*)&Afrag[(kk * 8 + wv) * 512 + lane * 8];
      const bf8 b0 = readB(0, kk);
      const bf8 b1 = readB(1, kk);
      acc0 = __builtin_amdgcn_mfma_f32_16x16x32_bf16(af, b0, acc0, 0, 0, 0);
      acc1 = __builtin_amdgcn_mfma_f32_16x16x32_bf16(af, b1, acc1, 0, 0, 0);
    }
    if (!isz) {  // block-diag einsum step
      const bf8 afd = cvt8(dax, day);
      const bf8 dbf0 = cvt8_tril(db0x, db0y, 8 * q, lcol);
      const bf8 dbf1 = cvt8_tril(db1x, db1y, 8 * q, 16 + lcol);
      acc0 = __builtin_amdgcn_mfma_f32_16x16x32_bf16(afd, dbf0, acc0, 0, 0, 0);
      acc1 = __builtin_amdgcn_mfma_f32_16x16x32_bf16(afd, dbf1, acc1, 0, 0, 0);
    }

    // ---- epilogue: both 64B halves of each 128B out line, back-to-back
    // (stores stay in flight across the raw barrier -- no drain)
    {
      const int c0 = 32 * T + lcol;
      const float m0 = mv[c0], m1 = mv[c0 + 16];
      #pragma unroll
      for (int rr = 0; rr < 4; ++rr) {
        const size_t rowoff = (size_t)(16 * wv + 4 * q + rr) * DT;
        out[rowoff + c0] = acc0[rr] + m0;
        out[rowoff + c0 + 16] = acc1[rr] + m1;
      }
    }

    BAR();                           // readers done (lgkm only; vmem in flight)
    if (have_next) stage_write(Tn);  // compiler inserts precise vmcnt per sv use
    BAR();                           // new panel visible (lgkm only)
  }
}

extern "C" void kernel_launch(void* const* d_in, const int* in_sizes, int n_in,
                              void* d_out, int out_size, void* d_ws, size_t ws_size,
                              hipStream_t stream) {
  const float* m   = (const float*)d_in[0];
  const float* Lz  = (const float*)d_in[1];
  const float* Ly  = (const float*)d_in[2];
  const float* Lyz = (const float*)d_in[3];
  const float* eps = (const float*)d_in[4];
  float* out = (float*)d_out;
  sv_kernel<<<dim3(256), dim3(512), 0, stream>>>(m, Lz, Ly, Lyz, eps, out);
}